// Round 1
// baseline (123.872 us; speedup 1.0000x reference)
//
#include <hip/hip_runtime.h>

// CP gate on 12 qubits applied to a batch of 64 complex state vectors.
// The dense U is diagonal: U[k][k] = 1 or e^{-i*phase}. We read the diagonal
// from the provided dense matrices (no hard-coded gate constants) and do the
// elementwise complex multiply:
//   out_re = dr*pr - di*pi ;  out_im = dr*pi + di*pr
// Output layout (stack([out_re, out_im])): [B*D] re block then [B*D] im block.

#define DIMQ  4096
#define BATCHQ 64

__global__ __launch_bounds__(256)
void cp_apply_kernel(const float* __restrict__ U_re,
                     const float* __restrict__ U_im,
                     const float* __restrict__ psi_re,
                     const float* __restrict__ psi_im,
                     float* __restrict__ out) {
    // Flat element-group index: each thread handles 4 consecutive floats of
    // the [B*D] space. B*D = 262144 -> 65536 groups -> 256 blocks x 256 thr.
    const int g    = blockIdx.x * blockDim.x + threadIdx.x;
    const int base = g << 2;                    // flat element index, 4-aligned
    const int k    = base & (DIMQ - 1);         // position within state vector

    const float4 pr = *reinterpret_cast<const float4*>(psi_re + base);
    const float4 pi = *reinterpret_cast<const float4*>(psi_im + base);

    // Diagonal gather: U[k*D + k], stride (D+1) floats between consecutive k.
    const size_t d0 = (size_t)k * (size_t)(DIMQ + 1);
    const size_t s  = (size_t)(DIMQ + 1);
    const float dr0 = U_re[d0];
    const float dr1 = U_re[d0 + s];
    const float dr2 = U_re[d0 + 2 * s];
    const float dr3 = U_re[d0 + 3 * s];
    const float di0 = U_im[d0];
    const float di1 = U_im[d0 + s];
    const float di2 = U_im[d0 + 2 * s];
    const float di3 = U_im[d0 + 3 * s];

    float4 ore, oim;
    ore.x = dr0 * pr.x - di0 * pi.x;  oim.x = dr0 * pi.x + di0 * pr.x;
    ore.y = dr1 * pr.y - di1 * pi.y;  oim.y = dr1 * pi.y + di1 * pr.y;
    ore.z = dr2 * pr.z - di2 * pi.z;  oim.z = dr2 * pi.z + di2 * pr.z;
    ore.w = dr3 * pr.w - di3 * pi.w;  oim.w = dr3 * pi.w + di3 * pr.w;

    *reinterpret_cast<float4*>(out + base) = ore;
    *reinterpret_cast<float4*>(out + (size_t)BATCHQ * DIMQ + base) = oim;
}

extern "C" void kernel_launch(void* const* d_in, const int* in_sizes, int n_in,
                              void* d_out, int out_size, void* d_ws, size_t ws_size,
                              hipStream_t stream) {
    (void)in_sizes; (void)n_in; (void)out_size; (void)d_ws; (void)ws_size;
    const float* U_re   = (const float*)d_in[0];
    const float* U_im   = (const float*)d_in[1];
    const float* psi_re = (const float*)d_in[2];
    const float* psi_im = (const float*)d_in[3];
    float* out = (float*)d_out;

    const int total_groups = (BATCHQ * DIMQ) / 4;   // 65536
    const int block = 256;
    const int grid  = total_groups / block;         // 256
    cp_apply_kernel<<<grid, block, 0, stream>>>(U_re, U_im, psi_re, psi_im, out);
}

// Round 2
// 123.517 us; speedup vs baseline: 1.0029x; 1.0029x over previous
//
#include <hip/hip_runtime.h>

// CP gate on 12 qubits applied to a batch of 64 complex state vectors.
// The dense U is diagonal. Two-phase:
//   Kernel A: extract diag (4096 re + 4096 im floats, 32 KB) into d_ws.
//             8192 strided loads total instead of 524288 per-thread gathers.
//   Kernel B: elementwise complex multiply, all accesses coalesced.
//   out_re = dr*pr - di*pi ;  out_im = dr*pi + di*pr
// Output layout (stack([out_re, out_im])): [B*D] re block then [B*D] im block.

#define DIMQ   4096
#define BATCHQ 64

__global__ __launch_bounds__(256)
void cp_extract_diag(const float* __restrict__ U_re,
                     const float* __restrict__ U_im,
                     float* __restrict__ diag /* [2*DIMQ]: re then im */) {
    const int k = blockIdx.x * blockDim.x + threadIdx.x;   // 0..4095
    const size_t idx = (size_t)k * (size_t)(DIMQ + 1);     // U[k][k]
    diag[k]        = U_re[idx];
    diag[DIMQ + k] = U_im[idx];
}

__global__ __launch_bounds__(256)
void cp_apply_kernel(const float* __restrict__ diag,
                     const float* __restrict__ psi_re,
                     const float* __restrict__ psi_im,
                     float* __restrict__ out) {
    const int g    = blockIdx.x * blockDim.x + threadIdx.x;
    const int base = g << 2;                    // flat element index, 4-aligned
    const int k    = base & (DIMQ - 1);         // 4-aligned within [0,4096)

    const float4 pr = *reinterpret_cast<const float4*>(psi_re + base);
    const float4 pi = *reinterpret_cast<const float4*>(psi_im + base);
    const float4 dr = *reinterpret_cast<const float4*>(diag + k);
    const float4 di = *reinterpret_cast<const float4*>(diag + DIMQ + k);

    float4 ore, oim;
    ore.x = dr.x * pr.x - di.x * pi.x;  oim.x = dr.x * pi.x + di.x * pr.x;
    ore.y = dr.y * pr.y - di.y * pi.y;  oim.y = dr.y * pi.y + di.y * pr.y;
    ore.z = dr.z * pr.z - di.z * pi.z;  oim.z = dr.z * pi.z + di.z * pr.z;
    ore.w = dr.w * pr.w - di.w * pi.w;  oim.w = dr.w * pi.w + di.w * pr.w;

    *reinterpret_cast<float4*>(out + base) = ore;
    *reinterpret_cast<float4*>(out + (size_t)BATCHQ * DIMQ + base) = oim;
}

// Fallback (single kernel, per-thread gather) if ws is too small — same math.
__global__ __launch_bounds__(256)
void cp_apply_gather(const float* __restrict__ U_re,
                     const float* __restrict__ U_im,
                     const float* __restrict__ psi_re,
                     const float* __restrict__ psi_im,
                     float* __restrict__ out) {
    const int g    = blockIdx.x * blockDim.x + threadIdx.x;
    const int base = g << 2;
    const int k    = base & (DIMQ - 1);

    const float4 pr = *reinterpret_cast<const float4*>(psi_re + base);
    const float4 pi = *reinterpret_cast<const float4*>(psi_im + base);

    const size_t d0 = (size_t)k * (size_t)(DIMQ + 1);
    const size_t s  = (size_t)(DIMQ + 1);
    float dr[4], di[4];
    #pragma unroll
    for (int j = 0; j < 4; ++j) { dr[j] = U_re[d0 + j * s]; di[j] = U_im[d0 + j * s]; }

    float4 ore, oim;
    ore.x = dr[0] * pr.x - di[0] * pi.x;  oim.x = dr[0] * pi.x + di[0] * pr.x;
    ore.y = dr[1] * pr.y - di[1] * pi.y;  oim.y = dr[1] * pi.y + di[1] * pr.y;
    ore.z = dr[2] * pr.z - di[2] * pi.z;  oim.z = dr[2] * pi.z + di[2] * pr.z;
    ore.w = dr[3] * pr.w - di[3] * pi.w;  oim.w = dr[3] * pi.w + di[3] * pr.w;

    *reinterpret_cast<float4*>(out + base) = ore;
    *reinterpret_cast<float4*>(out + (size_t)BATCHQ * DIMQ + base) = oim;
}

extern "C" void kernel_launch(void* const* d_in, const int* in_sizes, int n_in,
                              void* d_out, int out_size, void* d_ws, size_t ws_size,
                              hipStream_t stream) {
    (void)in_sizes; (void)n_in; (void)out_size;
    const float* U_re   = (const float*)d_in[0];
    const float* U_im   = (const float*)d_in[1];
    const float* psi_re = (const float*)d_in[2];
    const float* psi_im = (const float*)d_in[3];
    float* out = (float*)d_out;

    const int total_groups = (BATCHQ * DIMQ) / 4;   // 65536
    const int block = 256;
    const int grid  = total_groups / block;         // 256

    if (ws_size >= (size_t)(2 * DIMQ) * sizeof(float)) {
        float* diag = (float*)d_ws;
        cp_extract_diag<<<DIMQ / block, block, 0, stream>>>(U_re, U_im, diag);
        cp_apply_kernel<<<grid, block, 0, stream>>>(diag, psi_re, psi_im, out);
    } else {
        cp_apply_gather<<<grid, block, 0, stream>>>(U_re, U_im, psi_re, psi_im, out);
    }
}